// Round 7
// baseline (239.680 us; speedup 1.0000x reference)
//
#include <hip/hip_runtime.h>
#include <math.h>

// Problem constants
#define L_SEQ   32768
#define H_DIM   256
#define P_DIM   128
#define P2      256      // 2*P interleaved (re,im)
#define T_CHUNK 32
#define NBLK    512      // GEMM blocks: 64 rows each = 2 chunks
#define ROWS    64       // rows per block

// workspace layout (float offsets)
#define WS_LB    0                      // Lambda_bar            256
#define WS_A32   256                    // Lambda_bar^32         256
#define WS_A64   512                    // Lambda_bar^64         256
#define WS_COEF  768                    // (Lb-1)/Lambda         256
#define WS_APOW  1024                   // [32][P2] Lb^{i+1}     8192
#define WS_E     9216                   // [512][P2] block summ  131072
#define WS_CB    140288                 // [512][P2] block carry 131072
#define WS_PACKS 271360                 // ushort packs (float offset)
#define WS_XS    402432                 // [L][P2] xs            8388608 floats
// ws_size ~256 MB (harness poisons 268 MB) -> plenty

typedef __attribute__((ext_vector_type(8))) short short8;
typedef __attribute__((ext_vector_type(4))) float f32x4;

#define SAK 40    // LDS k-stride (ushorts) for A slices (32 + 8 pad)
#define SBK 40    // LDS k-stride (ushorts) for B slices
#define STL 260   // LDS float stride for scan tile

// ---------------------------------------------------------------------------
__device__ __forceinline__ void split_bf16(float v, ushort& hi, ushort& lo) {
    union { float f; unsigned u; } a; a.f = v;
    unsigned r = a.u + 0x7FFFu + ((a.u >> 16) & 1u);   // RNE to bf16
    hi = (ushort)(r >> 16);
    union { unsigned u; float f; } hf; hf.u = ((unsigned)hi) << 16;
    float rem = v - hf.f;
    union { float f; unsigned u; } b; b.f = rem;
    unsigned r2 = b.u + 0x7FFFu + ((b.u >> 16) & 1u);
    lo = (ushort)(r2 >> 16);
}

// two packed complex: returns A*x + f  (layout r0,i0,r1,i1)
__device__ __forceinline__ float4 cfma2(const float4 A, const float4 x, const float4 f) {
    float4 o;
    o.x = A.x * x.x - A.y * x.y + f.x;
    o.y = A.x * x.y + A.y * x.x + f.y;
    o.z = A.z * x.z - A.w * x.w + f.z;
    o.w = A.z * x.w + A.w * x.z + f.w;
    return o;
}

// ---------------------------------------------------------------------------
// Setup 1: per-p quantities. 1 block, 128 threads.
__global__ void k_setup_p(const float* __restrict__ lre, const float* __restrict__ lim,
                          const float* __restrict__ lstep, float* __restrict__ ws) {
    int p = threadIdx.x;
    if (p >= P_DIM) return;
    float step = expf(lstep[p]);
    float lr = lre[p], li = lim[p];
    float z = lr * step, y = li * step;
    float er = expf(z);
    ws[WS_LB + 2*p]     = er * cosf(y);
    ws[WS_LB + 2*p + 1] = er * sinf(y);
    double zd = (double)z, yd = (double)y;
    {   // Lb^32 (chunk advance)
        double ed = exp(zd * 32.0);
        ws[WS_A32 + 2*p]     = (float)(ed * cos(yd * 32.0));
        ws[WS_A32 + 2*p + 1] = (float)(ed * sin(yd * 32.0));
    }
    {   // Lb^64 (block advance, 2 chunks)
        double ed = exp(zd * 64.0);
        ws[WS_A64 + 2*p]     = (float)(ed * cos(yd * 64.0));
        ws[WS_A64 + 2*p + 1] = (float)(ed * sin(yd * 64.0));
    }
    for (int i = 0; i < 32; i++) {   // Apow[i] = Lb^{i+1}
        double m = (double)(i + 1);
        double ed = exp(zd * m);
        ws[WS_APOW + i*P2 + 2*p]     = (float)(ed * cos(yd * m));
        ws[WS_APOW + i*P2 + 2*p + 1] = (float)(ed * sin(yd * m));
    }
    float lbr = ws[WS_LB + 2*p], lbi = ws[WS_LB + 2*p + 1];
    float a = lbr - 1.0f, b = lbi;
    float den = lr*lr + li*li;
    ws[WS_COEF + 2*p]     = (a*lr + b*li) / den;
    ws[WS_COEF + 2*p + 1] = (b*lr - a*li) / den;
}

// ---------------------------------------------------------------------------
// Setup 2: build split-bf16 packed weights, layout [n][k] (k contiguous).
__global__ void k_setup_mats(const float* __restrict__ B, const float* __restrict__ C,
                             const float* __restrict__ coef,
                             ushort* __restrict__ w1h, ushort* __restrict__ w1l,
                             ushort* __restrict__ w2h, ushort* __restrict__ w2l) {
    int t = blockIdx.x * blockDim.x + threadIdx.x;   // 0..16383
    for (int e = t; e < P_DIM * H_DIM; e += 64 * 256) {
        int p = e >> 8;          // 0..127
        int h = e & 255;         // 0..255
        float br = B[(size_t)(p*H_DIM + h)*2 + 0];
        float bi = B[(size_t)(p*H_DIM + h)*2 + 1];
        float cr = coef[2*p], ci = coef[2*p + 1];
        float v1r = cr*br - ci*bi;
        float v1i = cr*bi + ci*br;
        ushort hi, lo;
        split_bf16(v1r, hi, lo);
        w1h[(size_t)(2*p)*256 + h] = hi;  w1l[(size_t)(2*p)*256 + h] = lo;
        split_bf16(v1i, hi, lo);
        w1h[(size_t)(2*p+1)*256 + h] = hi; w1l[(size_t)(2*p+1)*256 + h] = lo;
        float Cr = C[(size_t)(h*P_DIM + p)*2 + 0];
        float Ci = C[(size_t)(h*P_DIM + p)*2 + 1];
        split_bf16(2.0f*Cr, hi, lo);
        w2h[(size_t)h*256 + 2*p] = hi;    w2l[(size_t)h*256 + 2*p] = lo;
        split_bf16(-2.0f*Ci, hi, lo);
        w2h[(size_t)h*256 + 2*p+1] = hi;  w2l[(size_t)h*256 + 2*p+1] = lo;
    }
}

// ---------------------------------------------------------------------------
// Carry: serial scan over 512 block summaries. 1 block, 64 threads.
__global__ void k_carry(const float* __restrict__ E, float* __restrict__ cb,
                        const float* __restrict__ a64) {
    const int q = threadIdx.x;   // 0..63
    const float4 A = *(const float4*)(a64 + 4 * q);
    float4 c = make_float4(0.f, 0.f, 0.f, 0.f);
    #pragma unroll 8
    for (int s = 0; s < NBLK; s++) {
        *(float4*)(cb + (size_t)s * P2 + 4 * q) = c;
        const float4 e = *(const float4*)(E + (size_t)s * P2 + 4 * q);
        c = cfma2(A, c, e);
    }
}

// ---------------------------------------------------------------------------
// MFMA split-bf16 GEMM: C[l][n] = sum_k A[l][k] * W[k][n]
// M=32768 (512 blocks x 64 rows), N=256 full, K=256.
// 256 threads = 4 waves (2M x 2N), per wave 2x8 tiles of 16x16x32.
// K-loop: BK=32 slices, A+B staged in LDS (single buffer, 2 barriers/kt),
// next slice register-prefetched during the MFMA phase. b-frags from LDS.
// BSPLIT: B lo-pack used (3 MFMA) else 2 MFMA (hh + lo*h).
// APPLY : staging adds Lb^{i+1} * carry (chunk carries rebuilt in LDS).
// SCAN  : epilogue dumps acc chunk-wise into an LDS tile (aliasing staging),
//         scans there, writes xs once + block summary E.
template<bool EPI, bool APPLY, bool SCAN, bool BSPLIT>
__global__ __launch_bounds__(256, 3) void k_gemm_mfma(
        const float* __restrict__ A, const ushort* __restrict__ Wh,
        const ushort* __restrict__ Wl, float* __restrict__ Cmat,
        const float* __restrict__ Dv, const float* __restrict__ U,
        const float* __restrict__ ws, float* __restrict__ Eout,
        const float* __restrict__ cbin) {
    constexpr int SMF4 = BSPLIT ? 3200 : 1920;   // float4s: 51200 / 30720 B
    __shared__ float4 SMraw[SMF4];
    __shared__ float  XC[2 * P2];
    ushort* Ah   = (ushort*)SMraw;               // [64][SAK]   2560
    ushort* Al   = Ah + ROWS * SAK;              //             2560
    ushort* Bh   = Al + ROWS * SAK;              // [256][SBK] 10240
    ushort* Bl   = Bh + 256 * SBK;               // (BSPLIT)   10240
    float*  Tile = (float*)SMraw;                // [32][STL] scan tile (alias)

    const int t      = threadIdx.x;
    const int lane   = t & 63;
    const int wave   = t >> 6;        // 0..3
    const int wm     = wave & 1;      // M half (32 rows)
    const int wn     = wave >> 1;     // N half (128 cols)
    const int lane16 = lane & 15;
    const int quad   = lane >> 4;
    const int blk    = blockIdx.x;
    const int l0     = blk * ROWS;

    // --- APPLY prologue: rebuild per-chunk carries into LDS ---------------
    if (APPLY) {
        if (t < 64) {
            const float4 A32 = *(const float4*)(ws + WS_A32 + 4 * t);
            float4 c = *(const float4*)(cbin + (size_t)blk * P2 + 4 * t);
            *(float4*)(XC + 4 * t) = c;
            const float4 xe = *(const float4*)(A + (size_t)(l0 + 31) * 256 + 4 * t);
            c = cfma2(A32, c, xe);
            *(float4*)(XC + P2 + 4 * t) = c;
        }
        __syncthreads();
    }

    f32x4 acc[2][8];
    #pragma unroll
    for (int i = 0; i < 2; i++)
        #pragma unroll
        for (int j = 0; j < 8; j++) acc[i][j] = (f32x4){0.f, 0.f, 0.f, 0.f};

    // staging indices
    const int am0 = t >> 3;            // A row, j=0 (0..31)
    const int am1 = (256 + t) >> 3;    // A row, j=1 (32..63)
    const int ac4 = t & 7;             // A float4 col within slice
    const int bn0 = t >> 2;            // B n row base (j adds 64)
    const int bc  = t & 3;             // B uint4 col within slice

    // register prefetch buffers
    float4 pA0, pA1;
    uint4  pBh[4], pBl[4];

    // preload slice 0
    pA0 = *(const float4*)(A + (size_t)(l0 + am0) * 256 + ac4 * 4);
    pA1 = *(const float4*)(A + (size_t)(l0 + am1) * 256 + ac4 * 4);
    #pragma unroll
    for (int j = 0; j < 4; j++) {
        int n = bn0 + j * 64;
        pBh[j] = *(const uint4*)(Wh + (size_t)n * 256 + bc * 8);
        if (BSPLIT) pBl[j] = *(const uint4*)(Wl + (size_t)n * 256 + bc * 8);
    }

    for (int kt = 0; kt < 8; kt++) {
        const int k0 = kt * 32;
        if (kt) __syncthreads();       // readers of previous slice done
        // ---- store prefetched slice to LDS ----
        {
            float4 ff[2] = {pA0, pA1};
            int    mm[2] = {am0, am1};
            #pragma unroll
            for (int j = 0; j < 2; j++) {
                float4 f = ff[j];
                int m = mm[j];
                if (APPLY) {
                    int g = m >> 5, i = m & 31;
                    int jk = k0 + ac4 * 4;
                    const float4 ap = *(const float4*)(ws + WS_APOW + (size_t)i * P2 + jk);
                    const float4 cr = *(const float4*)(XC + g * P2 + jk);
                    f = cfma2(ap, cr, f);
                }
                ushort4 h4, l4;
                split_bf16(f.x, h4.x, l4.x);
                split_bf16(f.y, h4.y, l4.y);
                split_bf16(f.z, h4.z, l4.z);
                split_bf16(f.w, h4.w, l4.w);
                *(ushort4*)(&Ah[m * SAK + ac4 * 4]) = h4;
                *(ushort4*)(&Al[m * SAK + ac4 * 4]) = l4;
            }
            #pragma unroll
            for (int j = 0; j < 4; j++) {
                int n = bn0 + j * 64;
                *(uint4*)(&Bh[n * SBK + bc * 8]) = pBh[j];
                if (BSPLIT) *(uint4*)(&Bl[n * SBK + bc * 8]) = pBl[j];
            }
        }
        __syncthreads();               // slice visible
        // ---- prefetch next slice (in flight during MFMA phase) ----
        if (kt < 7) {
            const int kn = k0 + 32;
            pA0 = *(const float4*)(A + (size_t)(l0 + am0) * 256 + kn + ac4 * 4);
            pA1 = *(const float4*)(A + (size_t)(l0 + am1) * 256 + kn + ac4 * 4);
            #pragma unroll
            for (int j = 0; j < 4; j++) {
                int n = bn0 + j * 64;
                pBh[j] = *(const uint4*)(Wh + (size_t)n * 256 + kn + bc * 8);
                if (BSPLIT) pBl[j] = *(const uint4*)(Wl + (size_t)n * 256 + kn + bc * 8);
            }
        }
        // ---- fragments + MFMA ----
        short8 ah[2], alo[2];
        #pragma unroll
        for (int mf = 0; mf < 2; mf++) {
            int m = wm * 32 + mf * 16 + lane16;
            ah[mf]  = *(const short8*)(&Ah[m * SAK + quad * 8]);
            alo[mf] = *(const short8*)(&Al[m * SAK + quad * 8]);
        }
        #pragma unroll
        for (int nf = 0; nf < 8; nf++) {
            int n = wn * 128 + nf * 16 + lane16;
            short8 bh = *(const short8*)(&Bh[n * SBK + quad * 8]);
            short8 bl;
            if (BSPLIT) bl = *(const short8*)(&Bl[n * SBK + quad * 8]);
            #pragma unroll
            for (int mf = 0; mf < 2; mf++) {
                acc[mf][nf] = __builtin_amdgcn_mfma_f32_16x16x32_bf16(ah[mf],  bh, acc[mf][nf], 0, 0, 0);
                if (BSPLIT)
                    acc[mf][nf] = __builtin_amdgcn_mfma_f32_16x16x32_bf16(ah[mf], bl, acc[mf][nf], 0, 0, 0);
                acc[mf][nf] = __builtin_amdgcn_mfma_f32_16x16x32_bf16(alo[mf], bh, acc[mf][nf], 0, 0, 0);
            }
        }
    }

    if (!SCAN) {
        // direct epilogue: C/D layout col=lane&15, row=quad*4+reg
        #pragma unroll
        for (int mf = 0; mf < 2; mf++) {
            #pragma unroll
            for (int nf = 0; nf < 8; nf++) {
                int row0 = l0 + wm * 32 + mf * 16 + quad * 4;
                int col  = wn * 128 + nf * 16 + lane16;
                #pragma unroll
                for (int r = 0; r < 4; r++) {
                    float v = acc[mf][nf][r];
                    if (EPI) v += Dv[col] * U[(size_t)(row0 + r) * 256 + col];
                    Cmat[(size_t)(row0 + r) * 256 + col] = v;
                }
            }
        }
    } else {
        // chunk-sequential: dump 32 rows into LDS tile, scan, write xs once
        __syncthreads();               // all waves done reading staging LDS
        #pragma unroll
        for (int ch = 0; ch < 2; ch++) {
            if (wm == ch) {
                #pragma unroll
                for (int mf = 0; mf < 2; mf++)
                    #pragma unroll
                    for (int nf = 0; nf < 8; nf++) {
                        int row = mf * 16 + quad * 4;
                        int col = wn * 128 + nf * 16 + lane16;
                        #pragma unroll
                        for (int r = 0; r < 4; r++)
                            Tile[(row + r) * STL + col] = acc[mf][nf][r];
                    }
            }
            __syncthreads();
            if (wave == 0) {
                const float4 Alb = *(const float4*)(ws + WS_LB + 4 * lane);
                float* gbase = Cmat + (size_t)(l0 + ch * 32) * 256 + 4 * lane;
                float4 x = make_float4(0.f, 0.f, 0.f, 0.f);
                #pragma unroll 8
                for (int i = 0; i < T_CHUNK; i++) {
                    const float4 f = *(const float4*)(Tile + i * STL + 4 * lane);
                    x = cfma2(Alb, x, f);
                    *(float4*)(gbase + (size_t)i * 256) = x;
                }
                *(float4*)(XC + ch * P2 + 4 * lane) = x;
            }
            __syncthreads();           // scan reads done before next dump
        }
        if (t < 64) {
            const float4 A32 = *(const float4*)(ws + WS_A32 + 4 * t);
            const float4 x0  = *(const float4*)(XC + 4 * t);
            const float4 x1  = *(const float4*)(XC + P2 + 4 * t);
            const float4 e   = cfma2(A32, x0, x1);
            *(float4*)(Eout + (size_t)blk * P2 + 4 * t) = e;
        }
    }
}

// ---------------------------------------------------------------------------
extern "C" void kernel_launch(void* const* d_in, const int* in_sizes, int n_in,
                              void* d_out, int out_size, void* d_ws, size_t ws_size,
                              hipStream_t stream) {
    const float* lre   = (const float*)d_in[0];  // Lambda_re (P)
    const float* lim   = (const float*)d_in[1];  // Lambda_im (P)
    const float* B     = (const float*)d_in[2];  // (P,H,2)
    const float* C     = (const float*)d_in[3];  // (H,P,2)
    const float* D     = (const float*)d_in[4];  // (H)
    const float* lstep = (const float*)d_in[5];  // (P)
    const float* u     = (const float*)d_in[6];  // (L,H)
    float* out = (float*)d_out;                  // (L,H) final output only
    float* ws  = (float*)d_ws;
    float* xs  = ws + WS_XS;                     // (L,P2) scan state
    ushort* wpk = (ushort*)(ws + WS_PACKS);
    ushort* w1h = wpk;
    ushort* w1l = wpk + 65536;
    ushort* w2h = wpk + 131072;
    ushort* w2l = wpk + 196608;

    k_setup_p<<<1, 128, 0, stream>>>(lre, lim, lstep, ws);
    k_setup_mats<<<64, 256, 0, stream>>>(B, C, ws + WS_COEF, w1h, w1l, w2h, w2l);
    // GEMM1: xs_local = scan_local(u @ W1) -> ws, block summaries E
    k_gemm_mfma<false, false, true, true><<<NBLK, 256, 0, stream>>>(
        u, w1h, w1l, xs, nullptr, nullptr, ws, ws + WS_E, nullptr);
    // carry across 512 blocks
    k_carry<<<1, 64, 0, stream>>>(ws + WS_E, ws + WS_CB, ws + WS_A64);
    // GEMM2: out = (xs_local + Lb^{i+1} carry) @ W2 + D*u
    k_gemm_mfma<true, true, false, false><<<NBLK, 256, 0, stream>>>(
        xs, w2h, w2l, out, D, u, ws, nullptr, ws + WS_CB);
}

// Round 8
// 206.707 us; speedup vs baseline: 1.1595x; 1.1595x over previous
//
#include <hip/hip_runtime.h>
#include <math.h>

// Problem constants
#define L_SEQ   32768
#define H_DIM   256
#define P_DIM   128
#define P2      256      // 2*P interleaved (re,im)
#define T_CHUNK 32
#define NBLK    1024     // GEMM blocks: 32 rows each = exactly 1 chunk
#define ROWS    32       // rows per block

// workspace layout (float offsets)
#define WS_LB    0                      // Lambda_bar            256
#define WS_A32   256                    // Lambda_bar^32         256
#define WS_A2048 512                    // Lambda_bar^2048       256
#define WS_COEF  768                    // (Lb-1)/Lambda         256
#define WS_APOW  1024                   // [32][P2] Lb^{i+1}     8192
#define WS_E     9216                   // [1024][P2] chunk summ 262144
#define WS_CB    271360                 // [1024][P2] carry      262144
#define WS_PACKS 533504                 // ushort packs (float offset)
#define WS_XS    664576                 // [L][P2] xs            8388608 floats
// total ~9.05M floats = ~36 MB (ws ~256 MB)

typedef __attribute__((ext_vector_type(8))) short short8;
typedef __attribute__((ext_vector_type(4))) float f32x4;

#define SAK 264   // LDS k-stride (ushorts) for A tile: 256 + 8 pad (2-way only)
#define STL 260   // LDS float stride for scan tile

// ---------------------------------------------------------------------------
__device__ __forceinline__ void split_bf16(float v, ushort& hi, ushort& lo) {
    union { float f; unsigned u; } a; a.f = v;
    unsigned r = a.u + 0x7FFFu + ((a.u >> 16) & 1u);   // RNE to bf16
    hi = (ushort)(r >> 16);
    union { unsigned u; float f; } hf; hf.u = ((unsigned)hi) << 16;
    float rem = v - hf.f;
    union { float f; unsigned u; } b; b.f = rem;
    unsigned r2 = b.u + 0x7FFFu + ((b.u >> 16) & 1u);
    lo = (ushort)(r2 >> 16);
}

// two packed complex: returns A*x + f  (layout r0,i0,r1,i1)
__device__ __forceinline__ float4 cfma2(const float4 A, const float4 x, const float4 f) {
    float4 o;
    o.x = A.x * x.x - A.y * x.y + f.x;
    o.y = A.x * x.y + A.y * x.x + f.y;
    o.z = A.z * x.z - A.w * x.w + f.z;
    o.w = A.z * x.w + A.w * x.z + f.w;
    return o;
}

// ---------------------------------------------------------------------------
// Setup 1: per-p quantities. 1 block, 128 threads.
__global__ void k_setup_p(const float* __restrict__ lre, const float* __restrict__ lim,
                          const float* __restrict__ lstep, float* __restrict__ ws) {
    int p = threadIdx.x;
    if (p >= P_DIM) return;
    float step = expf(lstep[p]);
    float lr = lre[p], li = lim[p];
    float z = lr * step, y = li * step;
    float er = expf(z);
    ws[WS_LB + 2*p]     = er * cosf(y);
    ws[WS_LB + 2*p + 1] = er * sinf(y);
    double zd = (double)z, yd = (double)y;
    {   // Lb^32 (chunk advance)
        double ed = exp(zd * 32.0);
        ws[WS_A32 + 2*p]     = (float)(ed * cos(yd * 32.0));
        ws[WS_A32 + 2*p + 1] = (float)(ed * sin(yd * 32.0));
    }
    {   // Lb^2048 (segment advance = 64 chunks)
        double ed = exp(zd * 2048.0);
        ws[WS_A2048 + 2*p]     = (float)(ed * cos(yd * 2048.0));
        ws[WS_A2048 + 2*p + 1] = (float)(ed * sin(yd * 2048.0));
    }
    for (int i = 0; i < 32; i++) {   // Apow[i] = Lb^{i+1}
        double m = (double)(i + 1);
        double ed = exp(zd * m);
        ws[WS_APOW + i*P2 + 2*p]     = (float)(ed * cos(yd * m));
        ws[WS_APOW + i*P2 + 2*p + 1] = (float)(ed * sin(yd * m));
    }
    float lbr = ws[WS_LB + 2*p], lbi = ws[WS_LB + 2*p + 1];
    float a = lbr - 1.0f, b = lbi;
    float den = lr*lr + li*li;
    ws[WS_COEF + 2*p]     = (a*lr + b*li) / den;
    ws[WS_COEF + 2*p + 1] = (b*lr - a*li) / den;
}

// ---------------------------------------------------------------------------
// Setup 2: build split-bf16 packed weights, layout [n][k] (k contiguous).
__global__ void k_setup_mats(const float* __restrict__ B, const float* __restrict__ C,
                             const float* __restrict__ coef,
                             ushort* __restrict__ w1h, ushort* __restrict__ w1l,
                             ushort* __restrict__ w2h, ushort* __restrict__ w2l) {
    int t = blockIdx.x * blockDim.x + threadIdx.x;   // 0..16383
    for (int e = t; e < P_DIM * H_DIM; e += 64 * 256) {
        int p = e >> 8;          // 0..127
        int h = e & 255;         // 0..255
        float br = B[(size_t)(p*H_DIM + h)*2 + 0];
        float bi = B[(size_t)(p*H_DIM + h)*2 + 1];
        float cr = coef[2*p], ci = coef[2*p + 1];
        float v1r = cr*br - ci*bi;
        float v1i = cr*bi + ci*br;
        ushort hi, lo;
        split_bf16(v1r, hi, lo);
        w1h[(size_t)(2*p)*256 + h] = hi;  w1l[(size_t)(2*p)*256 + h] = lo;
        split_bf16(v1i, hi, lo);
        w1h[(size_t)(2*p+1)*256 + h] = hi; w1l[(size_t)(2*p+1)*256 + h] = lo;
        float Cr = C[(size_t)(h*P_DIM + p)*2 + 0];
        float Ci = C[(size_t)(h*P_DIM + p)*2 + 1];
        split_bf16(2.0f*Cr, hi, lo);
        w2h[(size_t)h*256 + 2*p] = hi;    w2l[(size_t)h*256 + 2*p] = lo;
        split_bf16(-2.0f*Ci, hi, lo);
        w2h[(size_t)h*256 + 2*p+1] = hi;  w2l[(size_t)h*256 + 2*p+1] = lo;
    }
}

// ---------------------------------------------------------------------------
// Carry (parallel, R3-proven): 1 block x 1024 thr = 16 segments x 64 lanes.
// Segment s covers chunks [64s, 64s+64). cb[g] = state entering chunk g.
__global__ __launch_bounds__(1024) void k_carry(const float* __restrict__ E,
                                                float* __restrict__ cb,
                                                const float* __restrict__ a32,
                                                const float* __restrict__ a2048) {
    __shared__ float Esh[16 * P2];
    const int t = threadIdx.x;
    const int s = t >> 6;      // segment 0..15
    const int q = t & 63;
    const float4 A   = *(const float4*)(a32 + 4 * q);
    const float4 AS  = *(const float4*)(a2048 + 4 * q);
    const float* xe = E + (size_t)s * 64 * P2 + 4 * q;
    // phase A: segment-local reduction
    float4 e = make_float4(0.f, 0.f, 0.f, 0.f);
    #pragma unroll 4
    for (int j = 0; j < 64; j++)
        e = cfma2(A, e, *(const float4*)(xe + (size_t)j * P2));
    *(float4*)(Esh + s * P2 + 4 * q) = e;
    __syncthreads();
    // phase B: prefix over segments
    float4 c = make_float4(0.f, 0.f, 0.f, 0.f);
    for (int j = 0; j < s; j++)
        c = cfma2(AS, c, *(const float4*)(Esh + j * P2 + 4 * q));
    // phase C: walk segment writing cb[g]
    float* cw = cb + (size_t)s * 64 * P2 + 4 * q;
    #pragma unroll 4
    for (int j = 0; j < 64; j++) {
        *(float4*)(cw + (size_t)j * P2) = c;
        c = cfma2(A, c, *(const float4*)(xe + (size_t)j * P2));
    }
}

// ---------------------------------------------------------------------------
// MFMA split-bf16 GEMM: C[l][n] = sum_k A[l][k] * W[k][n]
// M=32768 (1024 blocks x 32 rows = 1 chunk), N=256 full, K=256.
// 256 threads = 4 waves; wave w owns N-quarter [64w, 64w+64); 2mf x 4nf tiles.
// A tile staged ONCE in LDS (split bf16); barrier-free K-loop; b-frags from
// global (L2-resident). acc = 32 VGPRs -> 4 waves/SIMD feasible.
// BSPLIT: B lo-pack used (3 MFMA) else 2 (hh + lo*h).
// APPLY : staging adds Apow[row] * cb[blk] (block == chunk).
// SCAN  : acc -> LDS tile (aliases staging), wave0 scans, writes xs + E.
template<bool EPI, bool APPLY, bool SCAN, bool BSPLIT>
__global__ __launch_bounds__(256, 4) void k_gemm_mfma(
        const float* __restrict__ A, const ushort* __restrict__ Wh,
        const ushort* __restrict__ Wl, float* __restrict__ Cmat,
        const float* __restrict__ Dv, const float* __restrict__ U,
        const float* __restrict__ ws, float* __restrict__ Eout,
        const float* __restrict__ cbin) {
    __shared__ float4 SMraw[2112];               // 33792 B
    ushort* Ah   = (ushort*)SMraw;               // [32][SAK]
    ushort* Al   = Ah + ROWS * SAK;
    float*  Tile = (float*)SMraw;                // [32][STL] = 33280 B (alias)

    const int t      = threadIdx.x;
    const int lane   = t & 63;
    const int wave   = t >> 6;        // 0..3 = N quarter
    const int lane16 = lane & 15;
    const int quad   = lane >> 4;
    const int blk    = blockIdx.x;
    const int l0     = blk * ROWS;

    // --- stage full A tile (32 x 256) into LDS, split bf16 ----------------
    #pragma unroll 4
    for (int j = 0; j < 8; j++) {
        int idx = j * 256 + t;
        int m  = idx >> 6;           // 0..31
        int c4 = idx & 63;           // float4 col
        float4 f = *(const float4*)(A + (size_t)(l0 + m) * 256 + c4 * 4);
        if (APPLY) {
            const float4 ap = *(const float4*)(ws + WS_APOW + (size_t)m * P2 + c4 * 4);
            const float4 cr = *(const float4*)(cbin + (size_t)blk * P2 + c4 * 4);
            f = cfma2(ap, cr, f);
        }
        ushort4 h4, l4;
        split_bf16(f.x, h4.x, l4.x);
        split_bf16(f.y, h4.y, l4.y);
        split_bf16(f.z, h4.z, l4.z);
        split_bf16(f.w, h4.w, l4.w);
        *(ushort4*)(&Ah[m * SAK + c4 * 4]) = h4;
        *(ushort4*)(&Al[m * SAK + c4 * 4]) = l4;
    }
    __syncthreads();

    f32x4 acc[2][4];
    #pragma unroll
    for (int i = 0; i < 2; i++)
        #pragma unroll
        for (int j = 0; j < 4; j++) acc[i][j] = (f32x4){0.f, 0.f, 0.f, 0.f};

    // b-frag base: quads of a lane16 form one contiguous 64 B segment
    const ushort* WhB = Wh + (size_t)(wave * 64 + lane16) * 256 + quad * 8;
    const ushort* WlB = Wl + (size_t)(wave * 64 + lane16) * 256 + quad * 8;

    // --- K-loop: barrier-free, no prefetch registers ----------------------
    #pragma unroll
    for (int kt = 0; kt < 8; kt++) {
        const int k0 = kt * 32;
        short8 ah[2], alo[2];
        #pragma unroll
        for (int mf = 0; mf < 2; mf++) {
            int m = mf * 16 + lane16;
            ah[mf]  = *(const short8*)(&Ah[m * SAK + k0 + quad * 8]);
            alo[mf] = *(const short8*)(&Al[m * SAK + k0 + quad * 8]);
        }
        #pragma unroll
        for (int nf = 0; nf < 4; nf++) {
            short8 bh = *(const short8*)(WhB + (size_t)nf * 16 * 256 + k0);
            short8 bl;
            if (BSPLIT) bl = *(const short8*)(WlB + (size_t)nf * 16 * 256 + k0);
            #pragma unroll
            for (int mf = 0; mf < 2; mf++) {
                acc[mf][nf] = __builtin_amdgcn_mfma_f32_16x16x32_bf16(ah[mf],  bh, acc[mf][nf], 0, 0, 0);
                if (BSPLIT)
                    acc[mf][nf] = __builtin_amdgcn_mfma_f32_16x16x32_bf16(ah[mf], bl, acc[mf][nf], 0, 0, 0);
                acc[mf][nf] = __builtin_amdgcn_mfma_f32_16x16x32_bf16(alo[mf], bh, acc[mf][nf], 0, 0, 0);
            }
        }
    }

    if (!SCAN) {
        // direct epilogue: C/D layout col=lane&15, row=quad*4+reg
        #pragma unroll
        for (int mf = 0; mf < 2; mf++) {
            #pragma unroll
            for (int nf = 0; nf < 4; nf++) {
                int row0 = l0 + mf * 16 + quad * 4;
                int col  = wave * 64 + nf * 16 + lane16;
                #pragma unroll
                for (int r = 0; r < 4; r++) {
                    float v = acc[mf][nf][r];
                    if (EPI) v += Dv[col] * U[(size_t)(row0 + r) * 256 + col];
                    Cmat[(size_t)(row0 + r) * 256 + col] = v;
                }
            }
        }
    } else {
        // dump acc into LDS tile (staging dead), scan chunk, write xs + E
        __syncthreads();
        #pragma unroll
        for (int mf = 0; mf < 2; mf++)
            #pragma unroll
            for (int nf = 0; nf < 4; nf++) {
                int row = mf * 16 + quad * 4;
                int col = wave * 64 + nf * 16 + lane16;
                #pragma unroll
                for (int r = 0; r < 4; r++)
                    Tile[(row + r) * STL + col] = acc[mf][nf][r];
            }
        __syncthreads();
        if (wave == 0) {
            const float4 Alb = *(const float4*)(ws + WS_LB + 4 * lane);
            float* gbase = Cmat + (size_t)l0 * 256 + 4 * lane;
            float4 x = make_float4(0.f, 0.f, 0.f, 0.f);
            #pragma unroll 8
            for (int i = 0; i < T_CHUNK; i++) {
                const float4 f = *(const float4*)(Tile + i * STL + 4 * lane);
                x = cfma2(Alb, x, f);
                *(float4*)(gbase + (size_t)i * 256) = x;
            }
            *(float4*)(Eout + (size_t)blk * P2 + 4 * lane) = x;
        }
    }
}

// ---------------------------------------------------------------------------
extern "C" void kernel_launch(void* const* d_in, const int* in_sizes, int n_in,
                              void* d_out, int out_size, void* d_ws, size_t ws_size,
                              hipStream_t stream) {
    const float* lre   = (const float*)d_in[0];  // Lambda_re (P)
    const float* lim   = (const float*)d_in[1];  // Lambda_im (P)
    const float* B     = (const float*)d_in[2];  // (P,H,2)
    const float* C     = (const float*)d_in[3];  // (H,P,2)
    const float* D     = (const float*)d_in[4];  // (H)
    const float* lstep = (const float*)d_in[5];  // (P)
    const float* u     = (const float*)d_in[6];  // (L,H)
    float* out = (float*)d_out;                  // (L,H) final output only
    float* ws  = (float*)d_ws;
    float* xs  = ws + WS_XS;                     // (L,P2) scan state
    ushort* wpk = (ushort*)(ws + WS_PACKS);
    ushort* w1h = wpk;
    ushort* w1l = wpk + 65536;
    ushort* w2h = wpk + 131072;
    ushort* w2l = wpk + 196608;

    k_setup_p<<<1, 128, 0, stream>>>(lre, lim, lstep, ws);
    k_setup_mats<<<64, 256, 0, stream>>>(B, C, ws + WS_COEF, w1h, w1l, w2h, w2l);
    // GEMM1: xs_local = scan_local(u @ W1) -> ws, chunk summaries E
    k_gemm_mfma<false, false, true, true><<<NBLK, 256, 0, stream>>>(
        u, w1h, w1l, xs, nullptr, nullptr, ws, ws + WS_E, nullptr);
    // carry across 1024 chunks (segmented parallel)
    k_carry<<<1, 1024, 0, stream>>>(ws + WS_E, ws + WS_CB,
                                    ws + WS_A32, ws + WS_A2048);
    // GEMM2: out = (xs_local + Apow*carry) @ W2 + D*u
    k_gemm_mfma<true, true, false, false><<<NBLK, 256, 0, stream>>>(
        xs, w2h, w2l, out, D, u, ws, nullptr, ws + WS_CB);
}